// Round 9
// baseline (1102.617 us; speedup 1.0000x reference)
//
#include <hip/hip_runtime.h>

#define BLK 256

constexpr int BB   = 2048;  // batch
constexpr int CH2  = 512;   // batch chunk for conv1/pool1/conv2
constexpr int NCH2 = BB / CH2;
constexpr int KD   = 2048;  // codebook size
constexpr int CD   = 400;   // feature dim

// ---------------- fused conv1 + pool1 (512 threads) ----------------
__global__ __launch_bounds__(512) void fused12_k(const float* __restrict__ x,
                                                 const float* __restrict__ c1w,
                                                 const float* __restrict__ c1b,
                                                 const float* __restrict__ p1w,
                                                 const float* __restrict__ p1b,
                                                 float* __restrict__ h2c, int b0) {
    int bi = blockIdx.x;
    int o0 = blockIdx.y * 33;
    __shared__ float xs[69 * 25];
    __shared__ float c1[20][67][9];
    __shared__ float w1s[540];
    __shared__ float wps[1200];
    __shared__ float b1s[20], bps[20];
    int tid = threadIdx.x;
    for (int i = tid; i < 540; i += 512) w1s[i] = c1w[i];
    for (int i = tid; i < 1200; i += 512) wps[i] = p1w[i];
    if (tid < 20) { b1s[tid] = c1b[tid]; bps[tid] = p1b[tid]; }
    const float* xb = x + (size_t)(b0 + bi) * 5000;
    int r0 = 2 * o0 - 1;
    for (int i = tid; i < 69 * 25; i += 512) {
        int r = r0 + i / 25;
        xs[i] = (r >= 0 && r < 200) ? xb[r * 25 + (i % 25)] : 0.f;
    }
    __syncthreads();
    // phase 1: conv1, items = 67 ri x 5 groups (4 oc each) = 335
    for (int it = tid; it < 67 * 5; it += 512) {
        int ri = it / 5, g = it % 5;
        int oc0 = g * 4;
        int r = r0 + ri;
        float acc[4][9];
        if (r >= 0 && r <= 197) {
#pragma unroll
            for (int o = 0; o < 4; ++o)
#pragma unroll
                for (int j = 0; j < 9; ++j) acc[o][j] = b1s[oc0 + o];
#pragma unroll
            for (int kd = 0; kd < 3; ++kd) {
                float xv[25];
                const float* xr = &xs[(ri + kd) * 25];
#pragma unroll
                for (int m = 0; m < 25; ++m) xv[m] = xr[m];
#pragma unroll
                for (int o = 0; o < 4; ++o) {
                    const float* wp1 = &w1s[(oc0 + o) * 27 + kd * 9];
#pragma unroll
                    for (int kh = 0; kh < 3; ++kh)
#pragma unroll
                        for (int kw = 0; kw < 3; ++kw) {
                            float w = wp1[kh * 3 + kw];
#pragma unroll
                            for (int oh = 0; oh < 3; ++oh)
#pragma unroll
                                for (int ow = 0; ow < 3; ++ow)
                                    acc[o][oh * 3 + ow] += xv[(oh + kh) * 5 + ow + kw] * w;
                        }
                }
            }
#pragma unroll
            for (int o = 0; o < 4; ++o)
#pragma unroll
                for (int j = 0; j < 9; ++j) c1[oc0 + o][ri][j] = fmaxf(acc[o][j], 0.f);
        } else {
#pragma unroll
            for (int o = 0; o < 4; ++o)
#pragma unroll
                for (int j = 0; j < 9; ++j) c1[oc0 + o][ri][j] = 0.f;
        }
    }
    __syncthreads();
    // phase 2: pool1, items = 33 oi x 5 groups = 165; ri = 2*oi + kd
    for (int it = tid; it < 33 * 5; it += 512) {
        int oi = it / 5, g = it % 5;
        int oc0 = g * 4;
        float acc[4][9];
#pragma unroll
        for (int o = 0; o < 4; ++o)
#pragma unroll
            for (int j = 0; j < 9; ++j) acc[o][j] = bps[oc0 + o];
        for (int ic = 0; ic < 20; ++ic) {
            float win[3][9];
#pragma unroll
            for (int kd = 0; kd < 3; ++kd)
#pragma unroll
                for (int j = 0; j < 9; ++j) win[kd][j] = c1[ic][2 * oi + kd][j];
#pragma unroll
            for (int o = 0; o < 4; ++o) {
                const float* wp = &wps[((oc0 + o) * 20 + ic) * 3];
#pragma unroll
                for (int kd = 0; kd < 3; ++kd) {
                    float w = wp[kd];
#pragma unroll
                    for (int j = 0; j < 9; ++j) acc[o][j] += win[kd][j] * w;
                }
            }
        }
#pragma unroll
        for (int o = 0; o < 4; ++o) {
            float* ou = h2c + (((size_t)bi * 20 + (oc0 + o)) * 99 + (o0 + oi)) * 9;
#pragma unroll
            for (int j = 0; j < 9; ++j) ou[j] = acc[o][j];
        }
    }
}

// ---------------- conv2 (512 threads, 14 runs of 8 od) ----------------
__global__ __launch_bounds__(512) void conv2b_k(const float* __restrict__ h2c,
                                                const float* __restrict__ w,
                                                const float* __restrict__ bias,
                                                float* __restrict__ h3, int b0) {
    int bi = blockIdx.x;
    __shared__ float h2s[10][101][9];
    __shared__ float ws[35 * 271];
    int tid = threadIdx.x;
    int oc = tid % 35, run = tid / 35;   // 14 runs, tid<490
    int od_start = run * 7;              // 0..91; run 13 covers 91..98
    bool active = tid < 490;
    float acc[8];
    float bv = active ? bias[oc] : 0.f;
#pragma unroll
    for (int i = 0; i < 8; ++i) acc[i] = bv;
    const float* src = h2c + (size_t)bi * 17820;
    for (int s = 0; s < 2; ++s) {
        for (int i = tid; i < 10 * 9; i += 512) {
            int ic = i / 9, j = i % 9;
            h2s[ic][0][j] = 0.f; h2s[ic][100][j] = 0.f;
        }
        for (int i = tid; i < 8910; i += 512) {
            int ic = i / 891;
            ((float*)h2s)[i + ic * 18 + 9] = src[s * 8910 + i];
        }
        for (int i = tid; i < 35 * 270; i += 512) {
            int o = i / 270, t = i % 270;
            ws[o * 271 + t] = w[(size_t)o * 540 + s * 270 + t];
        }
        __syncthreads();
        if (active) {
            const float* wp = &ws[oc * 271];
            for (int ic = 0; ic < 10; ++ic) {
#pragma unroll
                for (int j = 0; j < 9; ++j) {
                    float win[10];
#pragma unroll
                    for (int t = 0; t < 10; ++t) win[t] = h2s[ic][od_start + t][j];
#pragma unroll
                    for (int kd = 0; kd < 3; ++kd) {
                        float wv = wp[(ic * 3 + kd) * 9 + j];
#pragma unroll
                        for (int i = 0; i < 8; ++i) acc[i] += win[i + kd] * wv;
                    }
                }
            }
        }
        __syncthreads();
    }
    if (active) {
        float* o = h3 + ((size_t)(b0 + bi) * 35 + oc) * 99 + od_start;
#pragma unroll
        for (int i = 0; i < 8; ++i) o[i] = fmaxf(acc[i], 0.f);
    }
}

// ---------------- fused pool2 + conv3 + conv4 (512 threads, runs of 4) ----------------
// Rows padded (105/55/57, odd) so full windows stay in-bounds and conflict-free.
__global__ __launch_bounds__(512) void fused345_k(const float* __restrict__ h3,
                                                  const float* __restrict__ w2, const float* __restrict__ b2,
                                                  const float* __restrict__ w3, const float* __restrict__ b3,
                                                  const float* __restrict__ w4, const float* __restrict__ b4,
                                                  float* __restrict__ h6) {
    int b = blockIdx.x;
    __shared__ float h3s[35][105];  // data 1..99; zeros 0, 100..104
    __shared__ float h4s[35][55];   // data 1..50; zeros 0, 51..54
    __shared__ float h5s[35][57];   // data 1..50; zeros 0, 51..56
    __shared__ float wbuf[3675];
    __shared__ float bbuf[35];
    int tid = threadIdx.x;
    int oc = tid % 35, run = tid / 35;   // 14 runs; pool2/conv3 use 13, conv4 uses 7
    for (int i = tid; i < 35; i += 512) {
        h3s[i][0] = 0.f;
#pragma unroll
        for (int t = 100; t < 105; ++t) h3s[i][t] = 0.f;
        h4s[i][0] = 0.f;
#pragma unroll
        for (int t = 51; t < 55; ++t) h4s[i][t] = 0.f;
        h5s[i][0] = 0.f;
#pragma unroll
        for (int t = 51; t < 57; ++t) h5s[i][t] = 0.f;
    }
    for (int i = tid; i < 35 * 99; i += 512) h3s[i / 99][1 + i % 99] = h3[(size_t)b * 3465 + i];
    for (int i = tid; i < 3675; i += 512) wbuf[i] = w2[i];
    if (tid < 35) bbuf[tid] = b2[tid];
    __syncthreads();
    // pool2: k3 s2 p1, no relu. padded p = 2*od+kd. 13 runs of 4 od.
    if (tid < 455) {
        int od0 = run * 4;               // 0..48
        float acc[4];
        float bv = bbuf[oc];
#pragma unroll
        for (int i = 0; i < 4; ++i) acc[i] = bv;
        const float* wrow = &wbuf[oc * 105];
        for (int ic = 0; ic < 35; ++ic) {
            float w0 = wrow[ic * 3], w1 = wrow[ic * 3 + 1], w2v = wrow[ic * 3 + 2];
            float win[9];
#pragma unroll
            for (int t = 0; t < 9; ++t) win[t] = h3s[ic][2 * od0 + t];  // max 104
#pragma unroll
            for (int i = 0; i < 4; ++i)
                acc[i] += win[2 * i] * w0 + win[2 * i + 1] * w1 + win[2 * i + 2] * w2v;
        }
#pragma unroll
        for (int i = 0; i < 4; ++i) {
            int od = od0 + i;
            if (od < 50) h4s[oc][1 + od] = acc[i];
        }
    }
    __syncthreads();
    for (int i = tid; i < 3675; i += 512) wbuf[i] = w3[i];
    if (tid < 35) bbuf[tid] = b3[tid];
    __syncthreads();
    // conv3: k3 s1 p1, relu. padded p = od+kd.
    if (tid < 455) {
        int od0 = run * 4;
        float acc[4];
        float bv = bbuf[oc];
#pragma unroll
        for (int i = 0; i < 4; ++i) acc[i] = bv;
        const float* wrow = &wbuf[oc * 105];
        for (int ic = 0; ic < 35; ++ic) {
            float w0 = wrow[ic * 3], w1 = wrow[ic * 3 + 1], w2v = wrow[ic * 3 + 2];
            float win[6];
#pragma unroll
            for (int t = 0; t < 6; ++t) win[t] = h4s[ic][od0 + t];  // max 53
#pragma unroll
            for (int i = 0; i < 4; ++i)
                acc[i] += win[i] * w0 + win[i + 1] * w1 + win[i + 2] * w2v;
        }
#pragma unroll
        for (int i = 0; i < 4; ++i) {
            int od = od0 + i;
            if (od < 50) h5s[oc][1 + od] = fmaxf(acc[i], 0.f);
        }
    }
    __syncthreads();
    for (int i = tid; i < 2450; i += 512) wbuf[i] = w4[i];
    if (tid < 35) bbuf[tid] = b4[tid];
    __syncthreads();
    // conv4: k2 s2 p1, relu, out D=26. padded p = 2*od+kd. 7 runs of 4.
    if (tid < 245) {
        int od0 = run * 4;               // 0..24
        float acc[4];
        float bv = bbuf[oc];
#pragma unroll
        for (int i = 0; i < 4; ++i) acc[i] = bv;
        const float* wrow = &wbuf[oc * 70];
        for (int ic = 0; ic < 35; ++ic) {
            float w0 = wrow[ic * 2], w1 = wrow[ic * 2 + 1];
            float win[8];
#pragma unroll
            for (int t = 0; t < 8; ++t) win[t] = h5s[ic][2 * od0 + t];  // max 55
#pragma unroll
            for (int i = 0; i < 4; ++i)
                acc[i] += win[2 * i] * w0 + win[2 * i + 1] * w1;
        }
#pragma unroll
        for (int i = 0; i < 4; ++i) {
            int od = od0 + i;
            if (od < 26) h6[(size_t)b * 910 + oc * 26 + od] = fmaxf(acc[i], 0.f);
        }
    }
}

// ---------------- NT-form tiled f32 GEMM, reg-prefetch + float4 LDS ----------------
template <int BM, int BN, int TM, int TN, bool GUARD, bool ARGMAX, bool SPLITK>
__global__ __launch_bounds__(256) void gemm_nt(const float* __restrict__ A,
                                               const float* __restrict__ B,
                                               const float* __restrict__ bias,
                                               float* __restrict__ C,
                                               const float* __restrict__ colscale,
                                               unsigned long long* __restrict__ keymax,
                                               int M, int N, int K) {
    constexpr int BK = 16;
    constexpr int AI = BM / 16, BI = BN / 16;
    __shared__ float As[BK][BM + 4];
    __shared__ float Bs[BK][BN + 4];
    int tid = threadIdx.x;
    int tx = tid % (BN / TN), ty = tid / (BN / TN);
    int row0 = blockIdx.y * BM;
    int col0 = blockIdx.x * BN;
    int kbase = 0, kend = K;
    if constexpr (SPLITK) {
        int nz = gridDim.z;
        int kchunk = (((K + nz - 1) / nz) + BK - 1) / BK * BK;
        kbase = blockIdx.z * kchunk;
        kend = kbase + kchunk;
        if (kend > K) kend = K;
    }
    int kk = tid % 16, ld = tid / 16;
    float ra[AI], rb[BI];
    auto loadA = [&](int k0, float* r) {
        int gk = k0 + kk;
#pragma unroll
        for (int i = 0; i < AI; ++i) {
            int gr = row0 + ld + 16 * i;
            float v = 0.f;
            if ((!GUARD && !SPLITK) || (gr < M && gk < kend)) v = A[(size_t)gr * K + gk];
            r[i] = v;
        }
    };
    auto loadB = [&](int k0, float* r) {
        int gk = k0 + kk;
#pragma unroll
        for (int i = 0; i < BI; ++i) {
            int gn = col0 + ld + 16 * i;
            float v = 0.f;
            if ((!GUARD && !SPLITK) || (gn < N && gk < kend)) v = B[(size_t)gn * K + gk];
            r[i] = v;
        }
    };
    auto stash = [&]() {
#pragma unroll
        for (int i = 0; i < AI; ++i) As[kk][ld + 16 * i] = ra[i];
#pragma unroll
        for (int i = 0; i < BI; ++i) Bs[kk][ld + 16 * i] = rb[i];
    };
    float acc[TM][TN] = {};
    int nt = (kend - kbase + BK - 1) / BK;
    loadA(kbase, ra); loadB(kbase, rb);
    stash();
    __syncthreads();
    for (int t = 0; t < nt; ++t) {
        bool more = (t + 1 < nt);
        if (more) { loadA(kbase + (t + 1) * BK, ra); loadB(kbase + (t + 1) * BK, rb); }
#pragma unroll
        for (int k = 0; k < BK; ++k) {
            float a[TM], b[TN];
            *(float4*)&a[0] = *(const float4*)&As[k][ty * TM];
            if constexpr (TM == 8) *(float4*)&a[4] = *(const float4*)&As[k][ty * TM + 4];
            *(float4*)&b[0] = *(const float4*)&Bs[k][tx * TN];
            if constexpr (TN == 8) *(float4*)&b[4] = *(const float4*)&Bs[k][tx * TN + 4];
#pragma unroll
            for (int i = 0; i < TM; ++i)
#pragma unroll
                for (int j = 0; j < TN; ++j) acc[i][j] += a[i] * b[j];
        }
        if (more) {
            __syncthreads();
            stash();
            __syncthreads();
        }
    }
    if constexpr (ARGMAX) {
        __shared__ unsigned long long red[BM][17];
#pragma unroll
        for (int i = 0; i < TM; ++i) {
            unsigned long long best = 0;
#pragma unroll
            for (int j = 0; j < TN; ++j) {
                int gc = col0 + tx * TN + j;
                float v = acc[i][j] * colscale[gc];
                unsigned u = __float_as_uint(v);
                unsigned ukey = (u & 0x80000000u) ? ~u : (u | 0x80000000u);
                unsigned long long key =
                    ((unsigned long long)ukey << 32) | (unsigned)(N - 1 - gc);
                if (key > best) best = key;
            }
            red[ty * TM + i][tx] = best;
        }
        __syncthreads();
        if (tid < BM) {
            unsigned long long best = 0;
#pragma unroll
            for (int q = 0; q < 16; ++q) {
                unsigned long long v = red[tid][q];
                if (v > best) best = v;
            }
            atomicMax(&keymax[row0 + tid], best);
        }
    } else {
#pragma unroll
        for (int i = 0; i < TM; ++i) {
            int gr = row0 + ty * TM + i;
            if (GUARD && gr >= M) continue;
#pragma unroll
            for (int j = 0; j < TN; ++j) {
                int gc = col0 + tx * TN + j;
                if (GUARD && gc >= N) continue;
                float v = acc[i][j];
                if constexpr (SPLITK) {
                    if (bias && blockIdx.z == 0) v += bias[gc];
                    atomicAdd(&C[(size_t)gr * N + gc], v);
                } else {
                    if (bias) v += bias[gc];
                    C[(size_t)gr * N + gc] = v;
                }
            }
        }
    }
}

// ---------------- G = mnew^T diag(1/||mnew_k||) mnew, split-K, reg-prefetch ----------------
__global__ __launch_bounds__(256) void gemm_tn_g(const float* __restrict__ mnew,
                                                 const float* __restrict__ nrm2,
                                                 float* __restrict__ G, int kchunk) {
    constexpr int BK = 16;
    __shared__ float As[BK][64];
    __shared__ float Bs[BK][64];
    int tid = threadIdx.x;
    int tx = tid % 16, ty = tid / 16;
    int c0 = blockIdx.y * 64, d0 = blockIdx.x * 64;
    int kbase = blockIdx.z * kchunk;
    int cl = tid % 64, kk0 = tid / 64;
    int gc0 = c0 + cl, gd0 = d0 + cl;
    bool cok = gc0 < CD, dok = gd0 < CD;
    float pa[4], pb[4];
    auto ld = [&](int k0) {
#pragma unroll
        for (int i = 0; i < 4; ++i) {
            int gk = k0 + kk0 + 4 * i;
            float s = 1.0f / fmaxf(nrm2[gk], 1e-12f);
            pa[i] = cok ? mnew[(size_t)gk * CD + gc0] * s : 0.f;
            pb[i] = dok ? mnew[(size_t)gk * CD + gd0] : 0.f;
        }
    };
    auto stash = [&]() {
#pragma unroll
        for (int i = 0; i < 4; ++i) {
            As[kk0 + 4 * i][cl] = pa[i];
            Bs[kk0 + 4 * i][cl] = pb[i];
        }
    };
    float acc[4][4] = {};
    int nt = kchunk / BK;
    ld(kbase); stash(); __syncthreads();
    for (int t = 0; t < nt; ++t) {
        bool more = (t + 1 < nt);
        if (more) ld(kbase + (t + 1) * BK);
#pragma unroll
        for (int k = 0; k < BK; ++k) {
            float a[4], b[4];
            *(float4*)&a[0] = *(const float4*)&As[k][ty * 4];
            *(float4*)&b[0] = *(const float4*)&Bs[k][tx * 4];
#pragma unroll
            for (int i = 0; i < 4; ++i)
#pragma unroll
                for (int j = 0; j < 4; ++j) acc[i][j] += a[i] * b[j];
        }
        if (more) { __syncthreads(); stash(); __syncthreads(); }
    }
#pragma unroll
    for (int i = 0; i < 4; ++i) {
        int gc = c0 + ty * 4 + i;
        if (gc >= CD) continue;
#pragma unroll
        for (int j = 0; j < 4; ++j) {
            int gd = d0 + tx * 4 + j;
            if (gd >= CD) continue;
            atomicAdd(&G[(size_t)gc * CD + gd], acc[i][j]);
        }
    }
}

// ---------------- helpers ----------------

__global__ __launch_bounds__(BLK) void rownorm_k(const float* __restrict__ in,
                                                 float* __restrict__ nrm, int rows, int cols) {
    int row  = blockIdx.x * (BLK / 64) + ((int)threadIdx.x / 64);
    int lane = threadIdx.x & 63;
    if (row >= rows) return;
    const float* p = in + (size_t)row * cols;
    float s = 0.f;
    for (int c = lane; c < cols; c += 64) { float v = p[c]; s += v * v; }
#pragma unroll
    for (int off = 32; off; off >>= 1) s += __shfl_down(s, off);
    if (lane == 0) nrm[row] = sqrtf(s);
}

__global__ __launch_bounds__(BLK) void scatter_k(const float* __restrict__ xx,
                                                 const unsigned long long* __restrict__ kb,
                                                 float* __restrict__ esum,
                                                 float* __restrict__ counts) {
    int idx = blockIdx.x * BLK + threadIdx.x;
    if (idx >= BB * CD) return;
    int n = idx / CD, c = idx % CD;
    int k = (KD - 1) - (int)(unsigned)(kb[n] & 0xffffffffull);
    atomicAdd(&esum[(size_t)k * CD + c], xx[idx]);
    if (c == 0) atomicAdd(&counts[k], 1.0f);
}

__global__ __launch_bounds__(BLK) void ss2_k(const float* __restrict__ esum,
                                             const float* __restrict__ counts,
                                             float* __restrict__ ss) {
    int k0 = blockIdx.x * 8;
    int tid = threadIdx.x;
    float a0 = 0.f, a1 = 0.f;
    for (int r = 0; r < 8; ++r) {
        int k = k0 + r;
        float rc = 1.0f / (counts[k] + 1e-6f);
        a0 += esum[(size_t)k * CD + tid] * rc;
        if (tid < CD - BLK) a1 += esum[(size_t)k * CD + BLK + tid] * rc;
    }
    atomicAdd(&ss[tid], a0);
    if (tid < CD - BLK) atomicAdd(&ss[BLK + tid], a1);
}

__global__ __launch_bounds__(BLK) void mnew_k(const float* __restrict__ m,
                                              const float* __restrict__ esum,
                                              const float* __restrict__ counts,
                                              const float* __restrict__ ss,
                                              float* __restrict__ mnew) {
    int idx = blockIdx.x * BLK + threadIdx.x;
    if (idx >= KD * CD) return;
    int k = idx / CD, c = idx % CD;
    float mean = esum[idx] / (counts[k] + 1e-6f);
    float pd = (mean - ss[c]) * (2.0f / ((float)KD * (float)(KD - 1)));
    mnew[idx] = m[idx] * 0.99f + (mean + pd) * 0.01f;
}

// Q[o][c] = sum_i cls_w[o][i] * up_w[i][c]
__global__ __launch_bounds__(BLK) void q_k(const float* __restrict__ cls_w,
                                           const float* __restrict__ up_w,
                                           float* __restrict__ Q) {
    int idx = blockIdx.x * BLK + threadIdx.x;
    if (idx >= 16 * CD) return;
    int o = idx / CD, c = idx % CD;
    float s = 0.f;
    for (int i = 0; i < CD; ++i) s += cls_w[o * CD + i] * up_w[(size_t)i * CD + c];
    Q[idx] = s;
}

// bias2[o] = cls_b[o] - sum_i up_b[i]*cls_w[o][i]
__global__ __launch_bounds__(64) void bias2_k(const float* __restrict__ cls_w,
                                              const float* __restrict__ up_b,
                                              const float* __restrict__ cls_b,
                                              float* __restrict__ bias2) {
    int o = threadIdx.x;
    if (o >= 16) return;
    float s = 0.f;
    for (int i = 0; i < CD; ++i) s += up_b[i] * cls_w[o * CD + i];
    bias2[o] = cls_b[o] - s;
}

// logits[b][o] = bias2[o] + fea[b].cls_w[o] - (t1[b]/u[b]) * Y[b].Q[o]
__global__ __launch_bounds__(BLK) void cls2_k(const float* __restrict__ fea,
                                              const float* __restrict__ Y,
                                              const float* __restrict__ t1,
                                              const float* __restrict__ u,
                                              const float* __restrict__ cls_w,
                                              const float* __restrict__ Q,
                                              const float* __restrict__ bias2,
                                              float* __restrict__ out) {
    int t = blockIdx.x * BLK + threadIdx.x;
    if (t >= BB * 16) return;
    int o = t % 16, b = t / 16;
    float rs = t1[b] / u[b];
    const float* fp = fea + (size_t)b * CD;
    const float* yp = Y + (size_t)b * CD;
    const float* cw = cls_w + o * CD;
    const float* qp = Q + o * CD;
    float a1 = 0.f, a2 = 0.f;
    for (int i = 0; i < CD; ++i) { a1 += fp[i] * cw[i]; a2 += yp[i] * qp[i]; }
    out[t] = bias2[o] + a1 - rs * a2;
}

// ---------------- launch ----------------

static inline int cdiv(int a, int b) { return (a + b - 1) / b; }

extern "C" void kernel_launch(void* const* d_in, const int* in_sizes, int n_in,
                              void* d_out, int out_size, void* d_ws, size_t ws_size,
                              hipStream_t stream) {
    const float* x       = (const float*)d_in[0];
    const float* conv1_w = (const float*)d_in[1];
    const float* conv1_b = (const float*)d_in[2];
    const float* pool1_w = (const float*)d_in[3];
    const float* pool1_b = (const float*)d_in[4];
    const float* conv2_w = (const float*)d_in[5];
    const float* conv2_b = (const float*)d_in[6];
    const float* pool2_w = (const float*)d_in[7];
    const float* pool2_b = (const float*)d_in[8];
    const float* conv3_w = (const float*)d_in[9];
    const float* conv3_b = (const float*)d_in[10];
    const float* conv4_w = (const float*)d_in[11];
    const float* conv4_b = (const float*)d_in[12];
    const float* feat_w  = (const float*)d_in[13];
    const float* feat_b  = (const float*)d_in[14];
    const float* feat1_w = (const float*)d_in[15];
    const float* feat1_b = (const float*)d_in[16];
    const float* mem     = (const float*)d_in[17];
    const float* up_w    = (const float*)d_in[18];
    const float* up_b    = (const float*)d_in[19];
    const float* cls_w   = (const float*)d_in[20];
    const float* cls_b   = (const float*)d_in[21];
    float* outp = (float*)d_out;

    float* ws = (float*)d_ws;
    size_t off = 0;
    auto alloc = [&](size_t n) { float* p = ws + off; off += n; return p; };

    unsigned long long* keybuf = (unsigned long long*)alloc(2 * BB);  // 8B aligned (off=0)
    float* h2c   = alloc((size_t)CH2 * 17820);
    float* h3    = alloc((size_t)BB * 35 * 99);
    float* h6    = alloc((size_t)BB * 910);
    float* fea   = alloc((size_t)BB * CD);   // fea,xx,Y contiguous -> one memset
    float* xx    = alloc((size_t)BB * CD);
    float* Y     = alloc((size_t)BB * CD);
    float* counts= alloc(KD);                // counts,esum,ssb contiguous -> one memset
    float* esum  = alloc((size_t)KD * CD);
    float* ssb   = alloc(CD);
    float* mnewb = alloc((size_t)KD * CD);
    float* G     = alloc((size_t)CD * CD);
    float* t1    = alloc(BB);
    float* u     = alloc(BB);
    float* Q     = alloc((size_t)16 * CD);
    float* bias2 = alloc(16);
    float* mnrm  = alloc(KD);
    float* nrm2  = alloc(KD);

    hipMemsetAsync(keybuf, 0, BB * sizeof(unsigned long long), stream);
    hipMemsetAsync(counts, 0, (KD + (size_t)KD * CD + CD) * sizeof(float), stream);
    hipMemsetAsync(fea, 0, (size_t)3 * BB * CD * sizeof(float), stream);
    hipMemsetAsync(G, 0, (size_t)CD * CD * sizeof(float), stream);

    // weight-only precomputes
    q_k<<<cdiv(16 * CD, BLK), BLK, 0, stream>>>(cls_w, up_w, Q);
    bias2_k<<<1, 64, 0, stream>>>(cls_w, up_b, cls_b, bias2);
    rownorm_k<<<cdiv(KD, 4), BLK, 0, stream>>>(mem, mnrm, KD, CD);

    // conv stack
    for (int ch = 0; ch < NCH2; ++ch) {
        int b0 = ch * CH2;
        dim3 g12(CH2, 3);
        fused12_k<<<g12, 512, 0, stream>>>(x, conv1_w, conv1_b, pool1_w, pool1_b, h2c, b0);
        conv2b_k<<<CH2, 512, 0, stream>>>(h2c, conv2_w, conv2_b, h3, b0);
    }
    fused345_k<<<BB, 512, 0, stream>>>(h3, pool2_w, pool2_b, conv3_w, conv3_b,
                                       conv4_w, conv4_b, h6);

    // fea = h6 @ feat_w^T + feat_b ; xx = fea @ feat1_w^T + feat1_b (split-K=2)
    {
        dim3 g(cdiv(CD, 64), BB / 64, 2);
        gemm_nt<64, 64, 4, 4, true, false, true><<<g, 256, 0, stream>>>(
            h6, feat_w, feat_b, fea, nullptr, nullptr, BB, CD, 910);
        gemm_nt<64, 64, 4, 4, true, false, true><<<g, 256, 0, stream>>>(
            fea, feat1_w, feat1_b, xx, nullptr, nullptr, BB, CD, CD);
    }

    rownorm_k<<<cdiv(BB, 4), BLK, 0, stream>>>(xx, t1, BB, CD);  // tend_1

    // fused score1 + argmax: raw = xx @ mem^T, key scaled by 1/||mem_k||
    {
        dim3 g(KD / 128, BB / 128);
        gemm_nt<128, 128, 8, 8, false, true, false><<<g, 256, 0, stream>>>(
            xx, mem, nullptr, nullptr, mnrm, keybuf, BB, KD, CD);
    }
    scatter_k<<<cdiv(BB * CD, BLK), BLK, 0, stream>>>(xx, keybuf, esum, counts);
    ss2_k<<<KD / 8, BLK, 0, stream>>>(esum, counts, ssb);
    mnew_k<<<cdiv(KD * CD, BLK), BLK, 0, stream>>>(mem, esum, counts, ssb, mnewb);

    rownorm_k<<<cdiv(KD, 4), BLK, 0, stream>>>(mnewb, nrm2, KD, CD);

    // G = mnew^T diag(1/||mnew_k||) mnew (symmetric), split-K over 8 chunks
    {
        dim3 g(cdiv(CD, 64), cdiv(CD, 64), 8);
        gemm_tn_g<<<g, 256, 0, stream>>>(mnewb, nrm2, G, KD / 8);
    }
    // Y = xx @ G (G symmetric -> NT form valid), split-K=2
    {
        dim3 g(cdiv(CD, 64), BB / 64, 2);
        gemm_nt<64, 64, 4, 4, true, false, true><<<g, 256, 0, stream>>>(
            xx, G, nullptr, Y, nullptr, nullptr, BB, CD, CD);
    }
    rownorm_k<<<cdiv(BB, 4), BLK, 0, stream>>>(Y, u, BB, CD);    // tend * t1g

    // logits = bias2 + fea@cls_w^T - (t1/u) * Y@Q^T
    cls2_k<<<cdiv(BB * 16, BLK), BLK, 0, stream>>>(fea, Y, t1, u, cls_w, Q, bias2, outp);
}

// Round 10
// 1011.700 us; speedup vs baseline: 1.0899x; 1.0899x over previous
//
#include <hip/hip_runtime.h>

#define BLK 256

constexpr int BB   = 2048;  // batch
constexpr int CH2  = 512;   // batch chunk for conv1/pool1/conv2
constexpr int NCH2 = BB / CH2;
constexpr int KD   = 2048;  // codebook size
constexpr int CD   = 400;   // feature dim

// ---------------- fused conv1 + pool1 (17-od stripes, 256 threads, 36KB LDS) ----------------
// grid (CH2, 6). Stripe s covers od2 in [s*17, min(s*17+17, 99)).
__global__ __launch_bounds__(256) void fused12_k(const float* __restrict__ x,
                                                 const float* __restrict__ c1w,
                                                 const float* __restrict__ c1b,
                                                 const float* __restrict__ p1w,
                                                 const float* __restrict__ p1b,
                                                 float* __restrict__ h2c, int b0) {
    int bi = blockIdx.x;
    int o0 = blockIdx.y * 17;
    int ocnt = 99 - o0; if (ocnt > 17) ocnt = 17;
    __shared__ float xs[37 * 25];
    __shared__ float c1[20][35][9];
    __shared__ float w1s[540];
    __shared__ float wps[1200];
    __shared__ float b1s[20], bps[20];
    int tid = threadIdx.x;
    for (int i = tid; i < 540; i += 256) w1s[i] = c1w[i];
    for (int i = tid; i < 1200; i += 256) wps[i] = p1w[i];
    if (tid < 20) { b1s[tid] = c1b[tid]; bps[tid] = p1b[tid]; }
    const float* xb = x + (size_t)(b0 + bi) * 5000;
    int r0 = 2 * o0 - 1;
    // stage x rows r0 .. r0+36 (zero-fill OOB)
    for (int i = tid; i < 37 * 25; i += 256) {
        int r = r0 + i / 25;
        xs[i] = (r >= 0 && r < 200) ? xb[r * 25 + (i % 25)] : 0.f;
    }
    __syncthreads();
    // phase 1: conv1, items = 35 ri x 5 groups (4 oc each) = 175 (single pass)
    for (int it = tid; it < 35 * 5; it += 256) {
        int ri = it / 5, g = it % 5;
        int oc0 = g * 4;
        int r = r0 + ri;
        float acc[4][9];
        if (r >= 0 && r <= 197) {
#pragma unroll
            for (int o = 0; o < 4; ++o)
#pragma unroll
                for (int j = 0; j < 9; ++j) acc[o][j] = b1s[oc0 + o];
#pragma unroll
            for (int kd = 0; kd < 3; ++kd) {
                float xv[25];
                const float* xr = &xs[(ri + kd) * 25];
#pragma unroll
                for (int m = 0; m < 25; ++m) xv[m] = xr[m];
#pragma unroll
                for (int o = 0; o < 4; ++o) {
                    const float* wp1 = &w1s[(oc0 + o) * 27 + kd * 9];
#pragma unroll
                    for (int kh = 0; kh < 3; ++kh)
#pragma unroll
                        for (int kw = 0; kw < 3; ++kw) {
                            float w = wp1[kh * 3 + kw];
#pragma unroll
                            for (int oh = 0; oh < 3; ++oh)
#pragma unroll
                                for (int ow = 0; ow < 3; ++ow)
                                    acc[o][oh * 3 + ow] += xv[(oh + kh) * 5 + ow + kw] * w;
                        }
                }
            }
#pragma unroll
            for (int o = 0; o < 4; ++o)
#pragma unroll
                for (int j = 0; j < 9; ++j) c1[oc0 + o][ri][j] = fmaxf(acc[o][j], 0.f);
        } else {
#pragma unroll
            for (int o = 0; o < 4; ++o)
#pragma unroll
                for (int j = 0; j < 9; ++j) c1[oc0 + o][ri][j] = 0.f;
        }
    }
    __syncthreads();
    // phase 2: pool1, items = ocnt oi x 5 groups <= 85; ri = 2*oi + kd (max 34)
    for (int it = tid; it < ocnt * 5; it += 256) {
        int oi = it / 5, g = it % 5;
        int oc0 = g * 4;
        float acc[4][9];
#pragma unroll
        for (int o = 0; o < 4; ++o)
#pragma unroll
            for (int j = 0; j < 9; ++j) acc[o][j] = bps[oc0 + o];
        for (int ic = 0; ic < 20; ++ic) {
            float win[3][9];
#pragma unroll
            for (int kd = 0; kd < 3; ++kd)
#pragma unroll
                for (int j = 0; j < 9; ++j) win[kd][j] = c1[ic][2 * oi + kd][j];
#pragma unroll
            for (int o = 0; o < 4; ++o) {
                const float* wp = &wps[((oc0 + o) * 20 + ic) * 3];
#pragma unroll
                for (int kd = 0; kd < 3; ++kd) {
                    float w = wp[kd];
#pragma unroll
                    for (int j = 0; j < 9; ++j) acc[o][j] += win[kd][j] * w;
                }
            }
        }
#pragma unroll
        for (int o = 0; o < 4; ++o) {
            float* ou = h2c + (((size_t)bi * 20 + (oc0 + o)) * 99 + (o0 + oi)) * 9;
#pragma unroll
            for (int j = 0; j < 9; ++j) ou[j] = acc[o][j];
        }
    }
}

// ---------------- conv2 (512 threads, 14 runs of 8 od) ----------------
__global__ __launch_bounds__(512) void conv2b_k(const float* __restrict__ h2c,
                                                const float* __restrict__ w,
                                                const float* __restrict__ bias,
                                                float* __restrict__ h3, int b0) {
    int bi = blockIdx.x;
    __shared__ float h2s[10][101][9];
    __shared__ float ws[35 * 271];
    int tid = threadIdx.x;
    int oc = tid % 35, run = tid / 35;   // 14 runs, tid<490
    int od_start = run * 7;              // 0..91; run 13 covers 91..98
    bool active = tid < 490;
    float acc[8];
    float bv = active ? bias[oc] : 0.f;
#pragma unroll
    for (int i = 0; i < 8; ++i) acc[i] = bv;
    const float* src = h2c + (size_t)bi * 17820;
    for (int s = 0; s < 2; ++s) {
        for (int i = tid; i < 10 * 9; i += 512) {
            int ic = i / 9, j = i % 9;
            h2s[ic][0][j] = 0.f; h2s[ic][100][j] = 0.f;
        }
        for (int i = tid; i < 8910; i += 512) {
            int ic = i / 891;
            ((float*)h2s)[i + ic * 18 + 9] = src[s * 8910 + i];
        }
        for (int i = tid; i < 35 * 270; i += 512) {
            int o = i / 270, t = i % 270;
            ws[o * 271 + t] = w[(size_t)o * 540 + s * 270 + t];
        }
        __syncthreads();
        if (active) {
            const float* wp = &ws[oc * 271];
            for (int ic = 0; ic < 10; ++ic) {
#pragma unroll
                for (int j = 0; j < 9; ++j) {
                    float win[10];
#pragma unroll
                    for (int t = 0; t < 10; ++t) win[t] = h2s[ic][od_start + t][j];
#pragma unroll
                    for (int kd = 0; kd < 3; ++kd) {
                        float wv = wp[(ic * 3 + kd) * 9 + j];
#pragma unroll
                        for (int i = 0; i < 8; ++i) acc[i] += win[i + kd] * wv;
                    }
                }
            }
        }
        __syncthreads();
    }
    if (active) {
        float* o = h3 + ((size_t)(b0 + bi) * 35 + oc) * 99 + od_start;
#pragma unroll
        for (int i = 0; i < 8; ++i) o[i] = fmaxf(acc[i], 0.f);
    }
}

// ---------------- fused pool2 + conv3 + conv4 (round-8 known-good: 256 thr, VGPR 68) ----------------
__global__ __launch_bounds__(256) void fused345_k(const float* __restrict__ h3,
                                                  const float* __restrict__ w2, const float* __restrict__ b2,
                                                  const float* __restrict__ w3, const float* __restrict__ b3,
                                                  const float* __restrict__ w4, const float* __restrict__ b4,
                                                  float* __restrict__ h6) {
    int b = blockIdx.x;
    __shared__ float h3s[35][101];
    __shared__ float h4s[35][53];
    __shared__ float h5s[35][53];
    __shared__ float wbuf[3675];
    __shared__ float bbuf[35];
    int tid = threadIdx.x;
    int oc = tid % 35, run = tid / 35;
    bool act = tid < 245;
    for (int i = tid; i < 35; i += 256) {
        h3s[i][0] = 0.f; h3s[i][100] = 0.f;
        h4s[i][0] = 0.f; h4s[i][51] = 0.f;
        h5s[i][0] = 0.f; h5s[i][51] = 0.f;
    }
    for (int i = tid; i < 35 * 99; i += 256) h3s[i / 99][1 + i % 99] = h3[(size_t)b * 3465 + i];
    for (int i = tid; i < 3675; i += 256) wbuf[i] = w2[i];
    if (tid < 35) bbuf[tid] = b2[tid];
    __syncthreads();
    if (act) {
        int od0 = run * 7;
        float acc[8];
        float bv = bbuf[oc];
#pragma unroll
        for (int i = 0; i < 8; ++i) acc[i] = bv;
        const float* wrow = &wbuf[oc * 105];
        for (int ic = 0; ic < 35; ++ic) {
            float w0 = wrow[ic * 3], w1 = wrow[ic * 3 + 1], w2v = wrow[ic * 3 + 2];
            float win[17];
#pragma unroll
            for (int t = 0; t < 17; ++t) win[t] = h3s[ic][2 * od0 + t];
#pragma unroll
            for (int i = 0; i < 8; ++i)
                acc[i] += win[2 * i] * w0 + win[2 * i + 1] * w1 + win[2 * i + 2] * w2v;
        }
#pragma unroll
        for (int i = 0; i < 8; ++i) h4s[oc][1 + od0 + i] = acc[i];
    }
    __syncthreads();
    for (int i = tid; i < 3675; i += 256) wbuf[i] = w3[i];
    if (tid < 35) bbuf[tid] = b3[tid];
    __syncthreads();
    if (act) {
        int od0 = run * 7;
        float acc[8];
        float bv = bbuf[oc];
#pragma unroll
        for (int i = 0; i < 8; ++i) acc[i] = bv;
        const float* wrow = &wbuf[oc * 105];
        for (int ic = 0; ic < 35; ++ic) {
            float w0 = wrow[ic * 3], w1 = wrow[ic * 3 + 1], w2v = wrow[ic * 3 + 2];
            float win[10];
#pragma unroll
            for (int t = 0; t < 10; ++t) win[t] = h4s[ic][od0 + t];
#pragma unroll
            for (int i = 0; i < 8; ++i)
                acc[i] += win[i] * w0 + win[i + 1] * w1 + win[i + 2] * w2v;
        }
#pragma unroll
        for (int i = 0; i < 8; ++i) h5s[oc][1 + od0 + i] = fmaxf(acc[i], 0.f);
    }
    __syncthreads();
    for (int i = tid; i < 2450; i += 256) wbuf[i] = w4[i];
    if (tid < 35) bbuf[tid] = b4[tid];
    __syncthreads();
    if (act) {
        int od0 = run * 4; if (od0 > 22) od0 = 22;
        float acc[4];
        float bv = bbuf[oc];
#pragma unroll
        for (int i = 0; i < 4; ++i) acc[i] = bv;
        const float* wrow = &wbuf[oc * 70];
        for (int ic = 0; ic < 35; ++ic) {
            float w0 = wrow[ic * 2], w1 = wrow[ic * 2 + 1];
            float win[8];
#pragma unroll
            for (int t = 0; t < 8; ++t) win[t] = h5s[ic][2 * od0 + t];
#pragma unroll
            for (int i = 0; i < 4; ++i)
                acc[i] += win[2 * i] * w0 + win[2 * i + 1] * w1;
        }
#pragma unroll
        for (int i = 0; i < 4; ++i) {
            int od = od0 + i;
            if (od < 26) h6[(size_t)b * 910 + oc * 26 + od] = fmaxf(acc[i], 0.f);
        }
    }
}

// ---------------- NT-form tiled f32 GEMM, reg-prefetch + float4 LDS ----------------
template <int BM, int BN, int TM, int TN, bool GUARD, bool ARGMAX, bool SPLITK>
__global__ __launch_bounds__(256) void gemm_nt(const float* __restrict__ A,
                                               const float* __restrict__ B,
                                               const float* __restrict__ bias,
                                               float* __restrict__ C,
                                               const float* __restrict__ colscale,
                                               unsigned long long* __restrict__ keymax,
                                               int M, int N, int K) {
    constexpr int BK = 16;
    constexpr int AI = BM / 16, BI = BN / 16;
    __shared__ float As[BK][BM + 4];
    __shared__ float Bs[BK][BN + 4];
    int tid = threadIdx.x;
    int tx = tid % (BN / TN), ty = tid / (BN / TN);
    int row0 = blockIdx.y * BM;
    int col0 = blockIdx.x * BN;
    int kbase = 0, kend = K;
    if constexpr (SPLITK) {
        int nz = gridDim.z;
        int kchunk = (((K + nz - 1) / nz) + BK - 1) / BK * BK;
        kbase = blockIdx.z * kchunk;
        kend = kbase + kchunk;
        if (kend > K) kend = K;
    }
    int kk = tid % 16, ld = tid / 16;
    float ra[AI], rb[BI];
    auto loadA = [&](int k0, float* r) {
        int gk = k0 + kk;
#pragma unroll
        for (int i = 0; i < AI; ++i) {
            int gr = row0 + ld + 16 * i;
            float v = 0.f;
            if ((!GUARD && !SPLITK) || (gr < M && gk < kend)) v = A[(size_t)gr * K + gk];
            r[i] = v;
        }
    };
    auto loadB = [&](int k0, float* r) {
        int gk = k0 + kk;
#pragma unroll
        for (int i = 0; i < BI; ++i) {
            int gn = col0 + ld + 16 * i;
            float v = 0.f;
            if ((!GUARD && !SPLITK) || (gn < N && gk < kend)) v = B[(size_t)gn * K + gk];
            r[i] = v;
        }
    };
    auto stash = [&]() {
#pragma unroll
        for (int i = 0; i < AI; ++i) As[kk][ld + 16 * i] = ra[i];
#pragma unroll
        for (int i = 0; i < BI; ++i) Bs[kk][ld + 16 * i] = rb[i];
    };
    float acc[TM][TN] = {};
    int nt = (kend - kbase + BK - 1) / BK;
    loadA(kbase, ra); loadB(kbase, rb);
    stash();
    __syncthreads();
    for (int t = 0; t < nt; ++t) {
        bool more = (t + 1 < nt);
        if (more) { loadA(kbase + (t + 1) * BK, ra); loadB(kbase + (t + 1) * BK, rb); }
#pragma unroll
        for (int k = 0; k < BK; ++k) {
            float a[TM], b[TN];
            *(float4*)&a[0] = *(const float4*)&As[k][ty * TM];
            if constexpr (TM == 8) *(float4*)&a[4] = *(const float4*)&As[k][ty * TM + 4];
            *(float4*)&b[0] = *(const float4*)&Bs[k][tx * TN];
            if constexpr (TN == 8) *(float4*)&b[4] = *(const float4*)&Bs[k][tx * TN + 4];
#pragma unroll
            for (int i = 0; i < TM; ++i)
#pragma unroll
                for (int j = 0; j < TN; ++j) acc[i][j] += a[i] * b[j];
        }
        if (more) {
            __syncthreads();
            stash();
            __syncthreads();
        }
    }
    if constexpr (ARGMAX) {
        __shared__ unsigned long long red[BM][17];
#pragma unroll
        for (int i = 0; i < TM; ++i) {
            unsigned long long best = 0;
#pragma unroll
            for (int j = 0; j < TN; ++j) {
                int gc = col0 + tx * TN + j;
                float v = acc[i][j] * colscale[gc];
                unsigned u = __float_as_uint(v);
                unsigned ukey = (u & 0x80000000u) ? ~u : (u | 0x80000000u);
                unsigned long long key =
                    ((unsigned long long)ukey << 32) | (unsigned)(N - 1 - gc);
                if (key > best) best = key;
            }
            red[ty * TM + i][tx] = best;
        }
        __syncthreads();
        if (tid < BM) {
            unsigned long long best = 0;
#pragma unroll
            for (int q = 0; q < 16; ++q) {
                unsigned long long v = red[tid][q];
                if (v > best) best = v;
            }
            atomicMax(&keymax[row0 + tid], best);
        }
    } else {
#pragma unroll
        for (int i = 0; i < TM; ++i) {
            int gr = row0 + ty * TM + i;
            if (GUARD && gr >= M) continue;
#pragma unroll
            for (int j = 0; j < TN; ++j) {
                int gc = col0 + tx * TN + j;
                if (GUARD && gc >= N) continue;
                float v = acc[i][j];
                if constexpr (SPLITK) {
                    if (bias && blockIdx.z == 0) v += bias[gc];
                    atomicAdd(&C[(size_t)gr * N + gc], v);
                } else {
                    if (bias) v += bias[gc];
                    C[(size_t)gr * N + gc] = v;
                }
            }
        }
    }
}

// ---------------- G = mnew^T diag(1/||mnew_k||) mnew, split-K, reg-prefetch ----------------
__global__ __launch_bounds__(256) void gemm_tn_g(const float* __restrict__ mnew,
                                                 const float* __restrict__ nrm2,
                                                 float* __restrict__ G, int kchunk) {
    constexpr int BK = 16;
    __shared__ float As[BK][64];
    __shared__ float Bs[BK][64];
    int tid = threadIdx.x;
    int tx = tid % 16, ty = tid / 16;
    int c0 = blockIdx.y * 64, d0 = blockIdx.x * 64;
    int kbase = blockIdx.z * kchunk;
    int cl = tid % 64, kk0 = tid / 64;
    int gc0 = c0 + cl, gd0 = d0 + cl;
    bool cok = gc0 < CD, dok = gd0 < CD;
    float pa[4], pb[4];
    auto ld = [&](int k0) {
#pragma unroll
        for (int i = 0; i < 4; ++i) {
            int gk = k0 + kk0 + 4 * i;
            float s = 1.0f / fmaxf(nrm2[gk], 1e-12f);
            pa[i] = cok ? mnew[(size_t)gk * CD + gc0] * s : 0.f;
            pb[i] = dok ? mnew[(size_t)gk * CD + gd0] : 0.f;
        }
    };
    auto stash = [&]() {
#pragma unroll
        for (int i = 0; i < 4; ++i) {
            As[kk0 + 4 * i][cl] = pa[i];
            Bs[kk0 + 4 * i][cl] = pb[i];
        }
    };
    float acc[4][4] = {};
    int nt = kchunk / BK;
    ld(kbase); stash(); __syncthreads();
    for (int t = 0; t < nt; ++t) {
        bool more = (t + 1 < nt);
        if (more) ld(kbase + (t + 1) * BK);
#pragma unroll
        for (int k = 0; k < BK; ++k) {
            float a[4], b[4];
            *(float4*)&a[0] = *(const float4*)&As[k][ty * 4];
            *(float4*)&b[0] = *(const float4*)&Bs[k][tx * 4];
#pragma unroll
            for (int i = 0; i < 4; ++i)
#pragma unroll
                for (int j = 0; j < 4; ++j) acc[i][j] += a[i] * b[j];
        }
        if (more) { __syncthreads(); stash(); __syncthreads(); }
    }
#pragma unroll
    for (int i = 0; i < 4; ++i) {
        int gc = c0 + ty * 4 + i;
        if (gc >= CD) continue;
#pragma unroll
        for (int j = 0; j < 4; ++j) {
            int gd = d0 + tx * 4 + j;
            if (gd >= CD) continue;
            atomicAdd(&G[(size_t)gc * CD + gd], acc[i][j]);
        }
    }
}

// ---------------- helpers ----------------

__global__ __launch_bounds__(BLK) void rownorm_k(const float* __restrict__ in,
                                                 float* __restrict__ nrm, int rows, int cols) {
    int row  = blockIdx.x * (BLK / 64) + ((int)threadIdx.x / 64);
    int lane = threadIdx.x & 63;
    if (row >= rows) return;
    const float* p = in + (size_t)row * cols;
    float s = 0.f;
    for (int c = lane; c < cols; c += 64) { float v = p[c]; s += v * v; }
#pragma unroll
    for (int off = 32; off; off >>= 1) s += __shfl_down(s, off);
    if (lane == 0) nrm[row] = sqrtf(s);
}

__global__ __launch_bounds__(BLK) void scatter_k(const float* __restrict__ xx,
                                                 const unsigned long long* __restrict__ kb,
                                                 float* __restrict__ esum,
                                                 float* __restrict__ counts) {
    int idx = blockIdx.x * BLK + threadIdx.x;
    if (idx >= BB * CD) return;
    int n = idx / CD, c = idx % CD;
    int k = (KD - 1) - (int)(unsigned)(kb[n] & 0xffffffffull);
    atomicAdd(&esum[(size_t)k * CD + c], xx[idx]);
    if (c == 0) atomicAdd(&counts[k], 1.0f);
}

__global__ __launch_bounds__(BLK) void ss2_k(const float* __restrict__ esum,
                                             const float* __restrict__ counts,
                                             float* __restrict__ ss) {
    int k0 = blockIdx.x * 8;
    int tid = threadIdx.x;
    float a0 = 0.f, a1 = 0.f;
    for (int r = 0; r < 8; ++r) {
        int k = k0 + r;
        float rc = 1.0f / (counts[k] + 1e-6f);
        a0 += esum[(size_t)k * CD + tid] * rc;
        if (tid < CD - BLK) a1 += esum[(size_t)k * CD + BLK + tid] * rc;
    }
    atomicAdd(&ss[tid], a0);
    if (tid < CD - BLK) atomicAdd(&ss[BLK + tid], a1);
}

__global__ __launch_bounds__(BLK) void mnew_k(const float* __restrict__ m,
                                              const float* __restrict__ esum,
                                              const float* __restrict__ counts,
                                              const float* __restrict__ ss,
                                              float* __restrict__ mnew) {
    int idx = blockIdx.x * BLK + threadIdx.x;
    if (idx >= KD * CD) return;
    int k = idx / CD, c = idx % CD;
    float mean = esum[idx] / (counts[k] + 1e-6f);
    float pd = (mean - ss[c]) * (2.0f / ((float)KD * (float)(KD - 1)));
    mnew[idx] = m[idx] * 0.99f + (mean + pd) * 0.01f;
}

// Q[o][c] = sum_i cls_w[o][i] * up_w[i][c]
__global__ __launch_bounds__(BLK) void q_k(const float* __restrict__ cls_w,
                                           const float* __restrict__ up_w,
                                           float* __restrict__ Q) {
    int idx = blockIdx.x * BLK + threadIdx.x;
    if (idx >= 16 * CD) return;
    int o = idx / CD, c = idx % CD;
    float s = 0.f;
    for (int i = 0; i < CD; ++i) s += cls_w[o * CD + i] * up_w[(size_t)i * CD + c];
    Q[idx] = s;
}

// bias2[o] = cls_b[o] - sum_i up_b[i]*cls_w[o][i]
__global__ __launch_bounds__(64) void bias2_k(const float* __restrict__ cls_w,
                                              const float* __restrict__ up_b,
                                              const float* __restrict__ cls_b,
                                              float* __restrict__ bias2) {
    int o = threadIdx.x;
    if (o >= 16) return;
    float s = 0.f;
    for (int i = 0; i < CD; ++i) s += up_b[i] * cls_w[o * CD + i];
    bias2[o] = cls_b[o] - s;
}

// logits[b][o] = bias2[o] + fea[b].cls_w[o] - (t1[b]/u[b]) * Y[b].Q[o]
__global__ __launch_bounds__(BLK) void cls2_k(const float* __restrict__ fea,
                                              const float* __restrict__ Y,
                                              const float* __restrict__ t1,
                                              const float* __restrict__ u,
                                              const float* __restrict__ cls_w,
                                              const float* __restrict__ Q,
                                              const float* __restrict__ bias2,
                                              float* __restrict__ out) {
    int t = blockIdx.x * BLK + threadIdx.x;
    if (t >= BB * 16) return;
    int o = t % 16, b = t / 16;
    float rs = t1[b] / u[b];
    const float* fp = fea + (size_t)b * CD;
    const float* yp = Y + (size_t)b * CD;
    const float* cw = cls_w + o * CD;
    const float* qp = Q + o * CD;
    float a1 = 0.f, a2 = 0.f;
    for (int i = 0; i < CD; ++i) { a1 += fp[i] * cw[i]; a2 += yp[i] * qp[i]; }
    out[t] = bias2[o] + a1 - rs * a2;
}

// ---------------- launch ----------------

static inline int cdiv(int a, int b) { return (a + b - 1) / b; }

extern "C" void kernel_launch(void* const* d_in, const int* in_sizes, int n_in,
                              void* d_out, int out_size, void* d_ws, size_t ws_size,
                              hipStream_t stream) {
    const float* x       = (const float*)d_in[0];
    const float* conv1_w = (const float*)d_in[1];
    const float* conv1_b = (const float*)d_in[2];
    const float* pool1_w = (const float*)d_in[3];
    const float* pool1_b = (const float*)d_in[4];
    const float* conv2_w = (const float*)d_in[5];
    const float* conv2_b = (const float*)d_in[6];
    const float* pool2_w = (const float*)d_in[7];
    const float* pool2_b = (const float*)d_in[8];
    const float* conv3_w = (const float*)d_in[9];
    const float* conv3_b = (const float*)d_in[10];
    const float* conv4_w = (const float*)d_in[11];
    const float* conv4_b = (const float*)d_in[12];
    const float* feat_w  = (const float*)d_in[13];
    const float* feat_b  = (const float*)d_in[14];
    const float* feat1_w = (const float*)d_in[15];
    const float* feat1_b = (const float*)d_in[16];
    const float* mem     = (const float*)d_in[17];
    const float* up_w    = (const float*)d_in[18];
    const float* up_b    = (const float*)d_in[19];
    const float* cls_w   = (const float*)d_in[20];
    const float* cls_b   = (const float*)d_in[21];
    float* outp = (float*)d_out;

    float* ws = (float*)d_ws;
    size_t off = 0;
    auto alloc = [&](size_t n) { float* p = ws + off; off += n; return p; };

    unsigned long long* keybuf = (unsigned long long*)alloc(2 * BB);  // 8B aligned (off=0)
    float* h2c   = alloc((size_t)CH2 * 17820);
    float* h3    = alloc((size_t)BB * 35 * 99);
    float* h6    = alloc((size_t)BB * 910);
    float* fea   = alloc((size_t)BB * CD);   // fea,xx,Y contiguous -> one memset
    float* xx    = alloc((size_t)BB * CD);
    float* Y     = alloc((size_t)BB * CD);
    float* counts= alloc(KD);                // counts,esum,ssb contiguous -> one memset
    float* esum  = alloc((size_t)KD * CD);
    float* ssb   = alloc(CD);
    float* mnewb = alloc((size_t)KD * CD);
    float* G     = alloc((size_t)CD * CD);
    float* t1    = alloc(BB);
    float* u     = alloc(BB);
    float* Q     = alloc((size_t)16 * CD);
    float* bias2 = alloc(16);
    float* mnrm  = alloc(KD);
    float* nrm2  = alloc(KD);

    hipMemsetAsync(keybuf, 0, BB * sizeof(unsigned long long), stream);
    hipMemsetAsync(counts, 0, (KD + (size_t)KD * CD + CD) * sizeof(float), stream);
    hipMemsetAsync(fea, 0, (size_t)3 * BB * CD * sizeof(float), stream);
    hipMemsetAsync(G, 0, (size_t)CD * CD * sizeof(float), stream);

    // weight-only precomputes
    q_k<<<cdiv(16 * CD, BLK), BLK, 0, stream>>>(cls_w, up_w, Q);
    bias2_k<<<1, 64, 0, stream>>>(cls_w, up_b, cls_b, bias2);
    rownorm_k<<<cdiv(KD, 4), BLK, 0, stream>>>(mem, mnrm, KD, CD);

    // conv stack
    for (int ch = 0; ch < NCH2; ++ch) {
        int b0 = ch * CH2;
        dim3 g12(CH2, 6);
        fused12_k<<<g12, 256, 0, stream>>>(x, conv1_w, conv1_b, pool1_w, pool1_b, h2c, b0);
        conv2b_k<<<CH2, 512, 0, stream>>>(h2c, conv2_w, conv2_b, h3, b0);
    }
    fused345_k<<<BB, 256, 0, stream>>>(h3, pool2_w, pool2_b, conv3_w, conv3_b,
                                       conv4_w, conv4_b, h6);

    // fea = h6 @ feat_w^T + feat_b ; xx = fea @ feat1_w^T + feat1_b (split-K=2)
    {
        dim3 g(cdiv(CD, 64), BB / 64, 2);
        gemm_nt<64, 64, 4, 4, true, false, true><<<g, 256, 0, stream>>>(
            h6, feat_w, feat_b, fea, nullptr, nullptr, BB, CD, 910);
        gemm_nt<64, 64, 4, 4, true, false, true><<<g, 256, 0, stream>>>(
            fea, feat1_w, feat1_b, xx, nullptr, nullptr, BB, CD, CD);
    }

    rownorm_k<<<cdiv(BB, 4), BLK, 0, stream>>>(xx, t1, BB, CD);  // tend_1

    // fused score1 + argmax: raw = xx @ mem^T, key scaled by 1/||mem_k||
    {
        dim3 g(KD / 128, BB / 128);
        gemm_nt<128, 128, 8, 8, false, true, false><<<g, 256, 0, stream>>>(
            xx, mem, nullptr, nullptr, mnrm, keybuf, BB, KD, CD);
    }
    scatter_k<<<cdiv(BB * CD, BLK), BLK, 0, stream>>>(xx, keybuf, esum, counts);
    ss2_k<<<KD / 8, BLK, 0, stream>>>(esum, counts, ssb);
    mnew_k<<<cdiv(KD * CD, BLK), BLK, 0, stream>>>(mem, esum, counts, ssb, mnewb);

    rownorm_k<<<cdiv(KD, 4), BLK, 0, stream>>>(mnewb, nrm2, KD, CD);

    // G = mnew^T diag(1/||mnew_k||) mnew (symmetric), split-K over 8 chunks
    {
        dim3 g(cdiv(CD, 64), cdiv(CD, 64), 8);
        gemm_tn_g<<<g, 256, 0, stream>>>(mnewb, nrm2, G, KD / 8);
    }
    // Y = xx @ G (G symmetric -> NT form valid), split-K=2
    {
        dim3 g(cdiv(CD, 64), BB / 64, 2);
        gemm_nt<64, 64, 4, 4, true, false, true><<<g, 256, 0, stream>>>(
            xx, G, nullptr, Y, nullptr, nullptr, BB, CD, CD);
    }
    rownorm_k<<<cdiv(BB, 4), BLK, 0, stream>>>(Y, u, BB, CD);    // tend * t1g

    // logits = bias2 + fea@cls_w^T - (t1/u) * Y@Q^T
    cls2_k<<<cdiv(BB * 16, BLK), BLK, 0, stream>>>(fea, Y, t1, u, cls_w, Q, bias2, outp);
}

// Round 11
// 942.659 us; speedup vs baseline: 1.1697x; 1.0732x over previous
//
#include <hip/hip_runtime.h>

#define BLK 256

constexpr int BB   = 2048;  // batch
constexpr int CH2  = 512;   // batch chunk for conv1/pool1/conv2
constexpr int NCH2 = BB / CH2;
constexpr int KD   = 2048;  // codebook size
constexpr int CD   = 400;   // feature dim

// ---------------- fused conv1 + pool1 (17-od stripes, 256 threads, 36KB LDS) ----------------
__global__ __launch_bounds__(256) void fused12_k(const float* __restrict__ x,
                                                 const float* __restrict__ c1w,
                                                 const float* __restrict__ c1b,
                                                 const float* __restrict__ p1w,
                                                 const float* __restrict__ p1b,
                                                 float* __restrict__ h2c, int b0) {
    int bi = blockIdx.x;
    int o0 = blockIdx.y * 17;
    int ocnt = 99 - o0; if (ocnt > 17) ocnt = 17;
    __shared__ float xs[37 * 25];
    __shared__ float c1[20][35][9];
    __shared__ float w1s[540];
    __shared__ float wps[1200];
    __shared__ float b1s[20], bps[20];
    int tid = threadIdx.x;
    for (int i = tid; i < 540; i += 256) w1s[i] = c1w[i];
    for (int i = tid; i < 1200; i += 256) wps[i] = p1w[i];
    if (tid < 20) { b1s[tid] = c1b[tid]; bps[tid] = p1b[tid]; }
    const float* xb = x + (size_t)(b0 + bi) * 5000;
    int r0 = 2 * o0 - 1;
    for (int i = tid; i < 37 * 25; i += 256) {
        int r = r0 + i / 25;
        xs[i] = (r >= 0 && r < 200) ? xb[r * 25 + (i % 25)] : 0.f;
    }
    __syncthreads();
    // phase 1: conv1, items = 35 ri x 5 groups (4 oc each) = 175 (single pass)
    for (int it = tid; it < 35 * 5; it += 256) {
        int ri = it / 5, g = it % 5;
        int oc0 = g * 4;
        int r = r0 + ri;
        float acc[4][9];
        if (r >= 0 && r <= 197) {
#pragma unroll
            for (int o = 0; o < 4; ++o)
#pragma unroll
                for (int j = 0; j < 9; ++j) acc[o][j] = b1s[oc0 + o];
#pragma unroll
            for (int kd = 0; kd < 3; ++kd) {
                float xv[25];
                const float* xr = &xs[(ri + kd) * 25];
#pragma unroll
                for (int m = 0; m < 25; ++m) xv[m] = xr[m];
#pragma unroll
                for (int o = 0; o < 4; ++o) {
                    const float* wp1 = &w1s[(oc0 + o) * 27 + kd * 9];
#pragma unroll
                    for (int kh = 0; kh < 3; ++kh)
#pragma unroll
                        for (int kw = 0; kw < 3; ++kw) {
                            float w = wp1[kh * 3 + kw];
#pragma unroll
                            for (int oh = 0; oh < 3; ++oh)
#pragma unroll
                                for (int ow = 0; ow < 3; ++ow)
                                    acc[o][oh * 3 + ow] += xv[(oh + kh) * 5 + ow + kw] * w;
                        }
                }
            }
#pragma unroll
            for (int o = 0; o < 4; ++o)
#pragma unroll
                for (int j = 0; j < 9; ++j) c1[oc0 + o][ri][j] = fmaxf(acc[o][j], 0.f);
        } else {
#pragma unroll
            for (int o = 0; o < 4; ++o)
#pragma unroll
                for (int j = 0; j < 9; ++j) c1[oc0 + o][ri][j] = 0.f;
        }
    }
    __syncthreads();
    // phase 2: pool1, items = ocnt oi x 5 groups <= 85; ri = 2*oi + kd (max 34)
    for (int it = tid; it < ocnt * 5; it += 256) {
        int oi = it / 5, g = it % 5;
        int oc0 = g * 4;
        float acc[4][9];
#pragma unroll
        for (int o = 0; o < 4; ++o)
#pragma unroll
            for (int j = 0; j < 9; ++j) acc[o][j] = bps[oc0 + o];
        for (int ic = 0; ic < 20; ++ic) {
            float win[3][9];
#pragma unroll
            for (int kd = 0; kd < 3; ++kd)
#pragma unroll
                for (int j = 0; j < 9; ++j) win[kd][j] = c1[ic][2 * oi + kd][j];
#pragma unroll
            for (int o = 0; o < 4; ++o) {
                const float* wp = &wps[((oc0 + o) * 20 + ic) * 3];
#pragma unroll
                for (int kd = 0; kd < 3; ++kd) {
                    float w = wp[kd];
#pragma unroll
                    for (int j = 0; j < 9; ++j) acc[o][j] += win[kd][j] * w;
                }
            }
        }
#pragma unroll
        for (int o = 0; o < 4; ++o) {
            float* ou = h2c + (((size_t)bi * 20 + (oc0 + o)) * 99 + (o0 + oi)) * 9;
#pragma unroll
            for (int j = 0; j < 9; ++j) ou[j] = acc[o][j];
        }
    }
}

// ---------------- conv2 v3: 2-oc groups, 4 ic-stages, 256 threads, 38KB LDS ----------------
// thread = (ocg of 2, run of 8 od): 18 x 14 = 252 active. Per (ic,j) the win[10]
// feeds 2 oc -> 16 reads : 48 FMA. ws rows padded to 137 (conflict-free), row 35 zeroed.
__global__ __launch_bounds__(256) void conv2b_k(const float* __restrict__ h2c,
                                                const float* __restrict__ w,
                                                const float* __restrict__ bias,
                                                float* __restrict__ h3, int b0) {
    int bi = blockIdx.x;
    __shared__ float h2s[5][101][9];   // 18.2KB, od padded both sides
    __shared__ float ws[36 * 137];     // 19.7KB
    int tid = threadIdx.x;
    int g = tid % 18, run = tid / 18;  // 18 oc-groups x 14 runs
    int oc0 = g * 2;                   // 0,2,..,34
    int od_start = run * 7;            // 0..91
    bool active = tid < 252;
    float acc[2][8];
    float bv0 = 0.f, bv1 = 0.f;
    if (active) {
        bv0 = bias[oc0];
        bv1 = (oc0 + 1 < 35) ? bias[oc0 + 1] : 0.f;
    }
#pragma unroll
    for (int i = 0; i < 8; ++i) { acc[0][i] = bv0; acc[1][i] = bv1; }
    const float* src = h2c + (size_t)bi * 17820;
    for (int s = 0; s < 4; ++s) {
        // zero od pads
        for (int i = tid; i < 5 * 9; i += 256) {
            int ic = i / 9, j = i % 9;
            h2s[ic][0][j] = 0.f; h2s[ic][100][j] = 0.f;
        }
        // load 5*99*9 = 4455 floats (coalesced)
        for (int i = tid; i < 4455; i += 256) {
            int ic = i / 891;
            ((float*)h2s)[i + ic * 18 + 9] = src[s * 4455 + i];
        }
        // load weight quarter: per oc 135 floats; zero row 35
        for (int i = tid; i < 35 * 135; i += 256) {
            int o = i / 135, t = i % 135;
            ws[o * 137 + t] = w[(size_t)o * 540 + s * 135 + t];
        }
        for (int i = tid; i < 137; i += 256) ws[35 * 137 + i] = 0.f;
        __syncthreads();
        if (active) {
            const float* wp0 = &ws[oc0 * 137];
            const float* wp1 = &ws[(oc0 + 1) * 137];
            for (int ic = 0; ic < 5; ++ic) {
#pragma unroll
                for (int j = 0; j < 9; ++j) {
                    float win[10];
#pragma unroll
                    for (int t = 0; t < 10; ++t) win[t] = h2s[ic][od_start + t][j];
#pragma unroll
                    for (int kd = 0; kd < 3; ++kd) {
                        float wv0 = wp0[(ic * 3 + kd) * 9 + j];
                        float wv1 = wp1[(ic * 3 + kd) * 9 + j];
#pragma unroll
                        for (int i = 0; i < 8; ++i) {
                            acc[0][i] += win[i + kd] * wv0;
                            acc[1][i] += win[i + kd] * wv1;
                        }
                    }
                }
            }
        }
        __syncthreads();
    }
    if (active) {
#pragma unroll
        for (int o = 0; o < 2; ++o) {
            int oc = oc0 + o;
            if (oc < 35) {
                float* ou = h3 + ((size_t)(b0 + bi) * 35 + oc) * 99 + od_start;
#pragma unroll
                for (int i = 0; i < 8; ++i) ou[i] = fmaxf(acc[o][i], 0.f);
            }
        }
    }
}

// ---------------- fused pool2 + conv3 + conv4 (h5s aliased onto h3s; 36.5KB -> 4 blk/CU) ----------------
__global__ __launch_bounds__(256) void fused345_k(const float* __restrict__ h3,
                                                  const float* __restrict__ w2, const float* __restrict__ b2,
                                                  const float* __restrict__ w3, const float* __restrict__ b3,
                                                  const float* __restrict__ w4, const float* __restrict__ b4,
                                                  float* __restrict__ h6) {
    int b = blockIdx.x;
    __shared__ float h3s[35][101];  // reused as h5s after pool2 (h3s dead)
    __shared__ float h4s[35][53];
    __shared__ float wbuf[3675];
    __shared__ float bbuf[35];
    float (*h5s)[101] = h3s;
    int tid = threadIdx.x;
    int oc = tid % 35, run = tid / 35;
    bool act = tid < 245;
    for (int i = tid; i < 35; i += 256) {
        h3s[i][0] = 0.f; h3s[i][100] = 0.f;
        h4s[i][0] = 0.f; h4s[i][51] = 0.f; h4s[i][52] = 0.f;
    }
    for (int i = tid; i < 35 * 99; i += 256) h3s[i / 99][1 + i % 99] = h3[(size_t)b * 3465 + i];
    for (int i = tid; i < 3675; i += 256) wbuf[i] = w2[i];
    if (tid < 35) bbuf[tid] = b2[tid];
    __syncthreads();
    // pool2: k3 s2 p1, no relu. padded p = 2*od+kd. 7 runs of 8 od.
    if (act) {
        int od0 = run * 7;
        float acc[8];
        float bv = bbuf[oc];
#pragma unroll
        for (int i = 0; i < 8; ++i) acc[i] = bv;
        const float* wrow = &wbuf[oc * 105];
        for (int ic = 0; ic < 35; ++ic) {
            float w0 = wrow[ic * 3], w1 = wrow[ic * 3 + 1], w2v = wrow[ic * 3 + 2];
            float win[17];
#pragma unroll
            for (int t = 0; t < 17; ++t) win[t] = h3s[ic][2 * od0 + t];
#pragma unroll
            for (int i = 0; i < 8; ++i)
                acc[i] += win[2 * i] * w0 + win[2 * i + 1] * w1 + win[2 * i + 2] * w2v;
        }
#pragma unroll
        for (int i = 0; i < 8; ++i) h4s[oc][1 + od0 + i] = acc[i];
    }
    __syncthreads();
    // stage w3; zero h5 pads (h3s region is dead now)
    for (int i = tid; i < 3675; i += 256) wbuf[i] = w3[i];
    if (tid < 35) bbuf[tid] = b3[tid];
    for (int i = tid; i < 35; i += 256) { h5s[i][0] = 0.f; h5s[i][51] = 0.f; }
    __syncthreads();
    // conv3: k3 s1 p1, relu. reads h4s, writes h5s (aliased region).
    if (act) {
        int od0 = run * 7;
        float acc[8];
        float bv = bbuf[oc];
#pragma unroll
        for (int i = 0; i < 8; ++i) acc[i] = bv;
        const float* wrow = &wbuf[oc * 105];
        for (int ic = 0; ic < 35; ++ic) {
            float w0 = wrow[ic * 3], w1 = wrow[ic * 3 + 1], w2v = wrow[ic * 3 + 2];
            float win[10];
#pragma unroll
            for (int t = 0; t < 10; ++t) win[t] = h4s[ic][od0 + t];
#pragma unroll
            for (int i = 0; i < 8; ++i)
                acc[i] += win[i] * w0 + win[i + 1] * w1 + win[i + 2] * w2v;
        }
#pragma unroll
        for (int i = 0; i < 8; ++i) h5s[oc][1 + od0 + i] = fmaxf(acc[i], 0.f);
    }
    __syncthreads();
    for (int i = tid; i < 2450; i += 256) wbuf[i] = w4[i];
    if (tid < 35) bbuf[tid] = b4[tid];
    __syncthreads();
    // conv4: k2 s2 p1, relu, out D=26. padded p = 2*od+kd (max 51).
    if (act) {
        int od0 = run * 4; if (od0 > 22) od0 = 22;
        float acc[4];
        float bv = bbuf[oc];
#pragma unroll
        for (int i = 0; i < 4; ++i) acc[i] = bv;
        const float* wrow = &wbuf[oc * 70];
        for (int ic = 0; ic < 35; ++ic) {
            float w0 = wrow[ic * 2], w1 = wrow[ic * 2 + 1];
            float win[8];
#pragma unroll
            for (int t = 0; t < 8; ++t) win[t] = h5s[ic][2 * od0 + t];
#pragma unroll
            for (int i = 0; i < 4; ++i)
                acc[i] += win[2 * i] * w0 + win[2 * i + 1] * w1;
        }
#pragma unroll
        for (int i = 0; i < 4; ++i) {
            int od = od0 + i;
            if (od < 26) h6[(size_t)b * 910 + oc * 26 + od] = fmaxf(acc[i], 0.f);
        }
    }
}

// ---------------- NT-form tiled f32 GEMM, reg-prefetch + float4 LDS ----------------
template <int BM, int BN, int TM, int TN, bool GUARD, bool ARGMAX, bool SPLITK>
__global__ __launch_bounds__(256) void gemm_nt(const float* __restrict__ A,
                                               const float* __restrict__ B,
                                               const float* __restrict__ bias,
                                               float* __restrict__ C,
                                               const float* __restrict__ colscale,
                                               unsigned long long* __restrict__ keymax,
                                               int M, int N, int K) {
    constexpr int BK = 16;
    constexpr int AI = BM / 16, BI = BN / 16;
    __shared__ float As[BK][BM + 4];
    __shared__ float Bs[BK][BN + 4];
    int tid = threadIdx.x;
    int tx = tid % (BN / TN), ty = tid / (BN / TN);
    int row0 = blockIdx.y * BM;
    int col0 = blockIdx.x * BN;
    int kbase = 0, kend = K;
    if constexpr (SPLITK) {
        int nz = gridDim.z;
        int kchunk = (((K + nz - 1) / nz) + BK - 1) / BK * BK;
        kbase = blockIdx.z * kchunk;
        kend = kbase + kchunk;
        if (kend > K) kend = K;
    }
    int kk = tid % 16, ld = tid / 16;
    float ra[AI], rb[BI];
    auto loadA = [&](int k0, float* r) {
        int gk = k0 + kk;
#pragma unroll
        for (int i = 0; i < AI; ++i) {
            int gr = row0 + ld + 16 * i;
            float v = 0.f;
            if ((!GUARD && !SPLITK) || (gr < M && gk < kend)) v = A[(size_t)gr * K + gk];
            r[i] = v;
        }
    };
    auto loadB = [&](int k0, float* r) {
        int gk = k0 + kk;
#pragma unroll
        for (int i = 0; i < BI; ++i) {
            int gn = col0 + ld + 16 * i;
            float v = 0.f;
            if ((!GUARD && !SPLITK) || (gn < N && gk < kend)) v = B[(size_t)gn * K + gk];
            r[i] = v;
        }
    };
    auto stash = [&]() {
#pragma unroll
        for (int i = 0; i < AI; ++i) As[kk][ld + 16 * i] = ra[i];
#pragma unroll
        for (int i = 0; i < BI; ++i) Bs[kk][ld + 16 * i] = rb[i];
    };
    float acc[TM][TN] = {};
    int nt = (kend - kbase + BK - 1) / BK;
    loadA(kbase, ra); loadB(kbase, rb);
    stash();
    __syncthreads();
    for (int t = 0; t < nt; ++t) {
        bool more = (t + 1 < nt);
        if (more) { loadA(kbase + (t + 1) * BK, ra); loadB(kbase + (t + 1) * BK, rb); }
#pragma unroll
        for (int k = 0; k < BK; ++k) {
            float a[TM], b[TN];
            *(float4*)&a[0] = *(const float4*)&As[k][ty * TM];
            if constexpr (TM == 8) *(float4*)&a[4] = *(const float4*)&As[k][ty * TM + 4];
            *(float4*)&b[0] = *(const float4*)&Bs[k][tx * TN];
            if constexpr (TN == 8) *(float4*)&b[4] = *(const float4*)&Bs[k][tx * TN + 4];
#pragma unroll
            for (int i = 0; i < TM; ++i)
#pragma unroll
                for (int j = 0; j < TN; ++j) acc[i][j] += a[i] * b[j];
        }
        if (more) {
            __syncthreads();
            stash();
            __syncthreads();
        }
    }
    if constexpr (ARGMAX) {
        __shared__ unsigned long long red[BM][17];
#pragma unroll
        for (int i = 0; i < TM; ++i) {
            unsigned long long best = 0;
#pragma unroll
            for (int j = 0; j < TN; ++j) {
                int gc = col0 + tx * TN + j;
                float v = acc[i][j] * colscale[gc];
                unsigned u = __float_as_uint(v);
                unsigned ukey = (u & 0x80000000u) ? ~u : (u | 0x80000000u);
                unsigned long long key =
                    ((unsigned long long)ukey << 32) | (unsigned)(N - 1 - gc);
                if (key > best) best = key;
            }
            red[ty * TM + i][tx] = best;
        }
        __syncthreads();
        if (tid < BM) {
            unsigned long long best = 0;
#pragma unroll
            for (int q = 0; q < 16; ++q) {
                unsigned long long v = red[tid][q];
                if (v > best) best = v;
            }
            atomicMax(&keymax[row0 + tid], best);
        }
    } else {
#pragma unroll
        for (int i = 0; i < TM; ++i) {
            int gr = row0 + ty * TM + i;
            if (GUARD && gr >= M) continue;
#pragma unroll
            for (int j = 0; j < TN; ++j) {
                int gc = col0 + tx * TN + j;
                if (GUARD && gc >= N) continue;
                float v = acc[i][j];
                if constexpr (SPLITK) {
                    if (bias && blockIdx.z == 0) v += bias[gc];
                    atomicAdd(&C[(size_t)gr * N + gc], v);
                } else {
                    if (bias) v += bias[gc];
                    C[(size_t)gr * N + gc] = v;
                }
            }
        }
    }
}

// ---------------- G = mnew^T diag(1/||mnew_k||) mnew, split-K, reg-prefetch ----------------
__global__ __launch_bounds__(256) void gemm_tn_g(const float* __restrict__ mnew,
                                                 const float* __restrict__ nrm2,
                                                 float* __restrict__ G, int kchunk) {
    constexpr int BK = 16;
    __shared__ float As[BK][64];
    __shared__ float Bs[BK][64];
    int tid = threadIdx.x;
    int tx = tid % 16, ty = tid / 16;
    int c0 = blockIdx.y * 64, d0 = blockIdx.x * 64;
    int kbase = blockIdx.z * kchunk;
    int cl = tid % 64, kk0 = tid / 64;
    int gc0 = c0 + cl, gd0 = d0 + cl;
    bool cok = gc0 < CD, dok = gd0 < CD;
    float pa[4], pb[4];
    auto ld = [&](int k0) {
#pragma unroll
        for (int i = 0; i < 4; ++i) {
            int gk = k0 + kk0 + 4 * i;
            float s = 1.0f / fmaxf(nrm2[gk], 1e-12f);
            pa[i] = cok ? mnew[(size_t)gk * CD + gc0] * s : 0.f;
            pb[i] = dok ? mnew[(size_t)gk * CD + gd0] : 0.f;
        }
    };
    auto stash = [&]() {
#pragma unroll
        for (int i = 0; i < 4; ++i) {
            As[kk0 + 4 * i][cl] = pa[i];
            Bs[kk0 + 4 * i][cl] = pb[i];
        }
    };
    float acc[4][4] = {};
    int nt = kchunk / BK;
    ld(kbase); stash(); __syncthreads();
    for (int t = 0; t < nt; ++t) {
        bool more = (t + 1 < nt);
        if (more) ld(kbase + (t + 1) * BK);
#pragma unroll
        for (int k = 0; k < BK; ++k) {
            float a[4], b[4];
            *(float4*)&a[0] = *(const float4*)&As[k][ty * 4];
            *(float4*)&b[0] = *(const float4*)&Bs[k][tx * 4];
#pragma unroll
            for (int i = 0; i < 4; ++i)
#pragma unroll
                for (int j = 0; j < 4; ++j) acc[i][j] += a[i] * b[j];
        }
        if (more) { __syncthreads(); stash(); __syncthreads(); }
    }
#pragma unroll
    for (int i = 0; i < 4; ++i) {
        int gc = c0 + ty * 4 + i;
        if (gc >= CD) continue;
#pragma unroll
        for (int j = 0; j < 4; ++j) {
            int gd = d0 + tx * 4 + j;
            if (gd >= CD) continue;
            atomicAdd(&G[(size_t)gc * CD + gd], acc[i][j]);
        }
    }
}

// ---------------- helpers ----------------

__global__ __launch_bounds__(BLK) void rownorm_k(const float* __restrict__ in,
                                                 float* __restrict__ nrm, int rows, int cols) {
    int row  = blockIdx.x * (BLK / 64) + ((int)threadIdx.x / 64);
    int lane = threadIdx.x & 63;
    if (row >= rows) return;
    const float* p = in + (size_t)row * cols;
    float s = 0.f;
    for (int c = lane; c < cols; c += 64) { float v = p[c]; s += v * v; }
#pragma unroll
    for (int off = 32; off; off >>= 1) s += __shfl_down(s, off);
    if (lane == 0) nrm[row] = sqrtf(s);
}

__global__ __launch_bounds__(BLK) void scatter_k(const float* __restrict__ xx,
                                                 const unsigned long long* __restrict__ kb,
                                                 float* __restrict__ esum,
                                                 float* __restrict__ counts) {
    int idx = blockIdx.x * BLK + threadIdx.x;
    if (idx >= BB * CD) return;
    int n = idx / CD, c = idx % CD;
    int k = (KD - 1) - (int)(unsigned)(kb[n] & 0xffffffffull);
    atomicAdd(&esum[(size_t)k * CD + c], xx[idx]);
    if (c == 0) atomicAdd(&counts[k], 1.0f);
}

__global__ __launch_bounds__(BLK) void ss2_k(const float* __restrict__ esum,
                                             const float* __restrict__ counts,
                                             float* __restrict__ ss) {
    int k0 = blockIdx.x * 8;
    int tid = threadIdx.x;
    float a0 = 0.f, a1 = 0.f;
    for (int r = 0; r < 8; ++r) {
        int k = k0 + r;
        float rc = 1.0f / (counts[k] + 1e-6f);
        a0 += esum[(size_t)k * CD + tid] * rc;
        if (tid < CD - BLK) a1 += esum[(size_t)k * CD + BLK + tid] * rc;
    }
    atomicAdd(&ss[tid], a0);
    if (tid < CD - BLK) atomicAdd(&ss[BLK + tid], a1);
}

__global__ __launch_bounds__(BLK) void mnew_k(const float* __restrict__ m,
                                              const float* __restrict__ esum,
                                              const float* __restrict__ counts,
                                              const float* __restrict__ ss,
                                              float* __restrict__ mnew) {
    int idx = blockIdx.x * BLK + threadIdx.x;
    if (idx >= KD * CD) return;
    int k = idx / CD, c = idx % CD;
    float mean = esum[idx] / (counts[k] + 1e-6f);
    float pd = (mean - ss[c]) * (2.0f / ((float)KD * (float)(KD - 1)));
    mnew[idx] = m[idx] * 0.99f + (mean + pd) * 0.01f;
}

// Q[o][c] = sum_i cls_w[o][i] * up_w[i][c]
__global__ __launch_bounds__(BLK) void q_k(const float* __restrict__ cls_w,
                                           const float* __restrict__ up_w,
                                           float* __restrict__ Q) {
    int idx = blockIdx.x * BLK + threadIdx.x;
    if (idx >= 16 * CD) return;
    int o = idx / CD, c = idx % CD;
    float s = 0.f;
    for (int i = 0; i < CD; ++i) s += cls_w[o * CD + i] * up_w[(size_t)i * CD + c];
    Q[idx] = s;
}

// bias2[o] = cls_b[o] - sum_i up_b[i]*cls_w[o][i]
__global__ __launch_bounds__(64) void bias2_k(const float* __restrict__ cls_w,
                                              const float* __restrict__ up_b,
                                              const float* __restrict__ cls_b,
                                              float* __restrict__ bias2) {
    int o = threadIdx.x;
    if (o >= 16) return;
    float s = 0.f;
    for (int i = 0; i < CD; ++i) s += up_b[i] * cls_w[o * CD + i];
    bias2[o] = cls_b[o] - s;
}

// logits[b][o] = bias2[o] + fea[b].cls_w[o] - (t1[b]/u[b]) * Y[b].Q[o]
__global__ __launch_bounds__(BLK) void cls2_k(const float* __restrict__ fea,
                                              const float* __restrict__ Y,
                                              const float* __restrict__ t1,
                                              const float* __restrict__ u,
                                              const float* __restrict__ cls_w,
                                              const float* __restrict__ Q,
                                              const float* __restrict__ bias2,
                                              float* __restrict__ out) {
    int t = blockIdx.x * BLK + threadIdx.x;
    if (t >= BB * 16) return;
    int o = t % 16, b = t / 16;
    float rs = t1[b] / u[b];
    const float* fp = fea + (size_t)b * CD;
    const float* yp = Y + (size_t)b * CD;
    const float* cw = cls_w + o * CD;
    const float* qp = Q + o * CD;
    float a1 = 0.f, a2 = 0.f;
    for (int i = 0; i < CD; ++i) { a1 += fp[i] * cw[i]; a2 += yp[i] * qp[i]; }
    out[t] = bias2[o] + a1 - rs * a2;
}

// ---------------- launch ----------------

static inline int cdiv(int a, int b) { return (a + b - 1) / b; }

extern "C" void kernel_launch(void* const* d_in, const int* in_sizes, int n_in,
                              void* d_out, int out_size, void* d_ws, size_t ws_size,
                              hipStream_t stream) {
    const float* x       = (const float*)d_in[0];
    const float* conv1_w = (const float*)d_in[1];
    const float* conv1_b = (const float*)d_in[2];
    const float* pool1_w = (const float*)d_in[3];
    const float* pool1_b = (const float*)d_in[4];
    const float* conv2_w = (const float*)d_in[5];
    const float* conv2_b = (const float*)d_in[6];
    const float* pool2_w = (const float*)d_in[7];
    const float* pool2_b = (const float*)d_in[8];
    const float* conv3_w = (const float*)d_in[9];
    const float* conv3_b = (const float*)d_in[10];
    const float* conv4_w = (const float*)d_in[11];
    const float* conv4_b = (const float*)d_in[12];
    const float* feat_w  = (const float*)d_in[13];
    const float* feat_b  = (const float*)d_in[14];
    const float* feat1_w = (const float*)d_in[15];
    const float* feat1_b = (const float*)d_in[16];
    const float* mem     = (const float*)d_in[17];
    const float* up_w    = (const float*)d_in[18];
    const float* up_b    = (const float*)d_in[19];
    const float* cls_w   = (const float*)d_in[20];
    const float* cls_b   = (const float*)d_in[21];
    float* outp = (float*)d_out;

    float* ws = (float*)d_ws;
    size_t off = 0;
    auto alloc = [&](size_t n) { float* p = ws + off; off += n; return p; };

    unsigned long long* keybuf = (unsigned long long*)alloc(2 * BB);  // 8B aligned (off=0)
    float* h2c   = alloc((size_t)CH2 * 17820);
    float* h3    = alloc((size_t)BB * 35 * 99);
    float* h6    = alloc((size_t)BB * 910);
    float* fea   = alloc((size_t)BB * CD);   // fea,xx,Y contiguous -> one memset
    float* xx    = alloc((size_t)BB * CD);
    float* Y     = alloc((size_t)BB * CD);
    float* counts= alloc(KD);                // counts,esum,ssb contiguous -> one memset
    float* esum  = alloc((size_t)KD * CD);
    float* ssb   = alloc(CD);
    float* mnewb = alloc((size_t)KD * CD);
    float* G     = alloc((size_t)CD * CD);
    float* t1    = alloc(BB);
    float* u     = alloc(BB);
    float* Q     = alloc((size_t)16 * CD);
    float* bias2 = alloc(16);
    float* mnrm  = alloc(KD);
    float* nrm2  = alloc(KD);

    hipMemsetAsync(keybuf, 0, BB * sizeof(unsigned long long), stream);
    hipMemsetAsync(counts, 0, (KD + (size_t)KD * CD + CD) * sizeof(float), stream);
    hipMemsetAsync(fea, 0, (size_t)3 * BB * CD * sizeof(float), stream);
    hipMemsetAsync(G, 0, (size_t)CD * CD * sizeof(float), stream);

    // weight-only precomputes
    q_k<<<cdiv(16 * CD, BLK), BLK, 0, stream>>>(cls_w, up_w, Q);
    bias2_k<<<1, 64, 0, stream>>>(cls_w, up_b, cls_b, bias2);
    rownorm_k<<<cdiv(KD, 4), BLK, 0, stream>>>(mem, mnrm, KD, CD);

    // conv stack
    for (int ch = 0; ch < NCH2; ++ch) {
        int b0 = ch * CH2;
        dim3 g12(CH2, 6);
        fused12_k<<<g12, 256, 0, stream>>>(x, conv1_w, conv1_b, pool1_w, pool1_b, h2c, b0);
        conv2b_k<<<CH2, 256, 0, stream>>>(h2c, conv2_w, conv2_b, h3, b0);
    }
    fused345_k<<<BB, 256, 0, stream>>>(h3, pool2_w, pool2_b, conv3_w, conv3_b,
                                       conv4_w, conv4_b, h6);

    // fea = h6 @ feat_w^T + feat_b ; xx = fea @ feat1_w^T + feat1_b (split-K=2)
    {
        dim3 g(cdiv(CD, 64), BB / 64, 2);
        gemm_nt<64, 64, 4, 4, true, false, true><<<g, 256, 0, stream>>>(
            h6, feat_w, feat_b, fea, nullptr, nullptr, BB, CD, 910);
        gemm_nt<64, 64, 4, 4, true, false, true><<<g, 256, 0, stream>>>(
            fea, feat1_w, feat1_b, xx, nullptr, nullptr, BB, CD, CD);
    }

    rownorm_k<<<cdiv(BB, 4), BLK, 0, stream>>>(xx, t1, BB, CD);  // tend_1

    // fused score1 + argmax: raw = xx @ mem^T, key scaled by 1/||mem_k||
    {
        dim3 g(KD / 128, BB / 128);
        gemm_nt<128, 128, 8, 8, false, true, false><<<g, 256, 0, stream>>>(
            xx, mem, nullptr, nullptr, mnrm, keybuf, BB, KD, CD);
    }
    scatter_k<<<cdiv(BB * CD, BLK), BLK, 0, stream>>>(xx, keybuf, esum, counts);
    ss2_k<<<KD / 8, BLK, 0, stream>>>(esum, counts, ssb);
    mnew_k<<<cdiv(KD * CD, BLK), BLK, 0, stream>>>(mem, esum, counts, ssb, mnewb);

    rownorm_k<<<cdiv(KD, 4), BLK, 0, stream>>>(mnewb, nrm2, KD, CD);

    // G = mnew^T diag(1/||mnew_k||) mnew (symmetric), split-K over 8 chunks
    {
        dim3 g(cdiv(CD, 64), cdiv(CD, 64), 8);
        gemm_tn_g<<<g, 256, 0, stream>>>(mnewb, nrm2, G, KD / 8);
    }
    // Y = xx @ G (G symmetric -> NT form valid), split-K=2
    {
        dim3 g(cdiv(CD, 64), BB / 64, 2);
        gemm_nt<64, 64, 4, 4, true, false, true><<<g, 256, 0, stream>>>(
            xx, G, nullptr, Y, nullptr, nullptr, BB, CD, CD);
    }
    rownorm_k<<<cdiv(BB, 4), BLK, 0, stream>>>(Y, u, BB, CD);    // tend * t1g

    // logits = bias2 + fea@cls_w^T - (t1/u) * Y@Q^T
    cls2_k<<<cdiv(BB * 16, BLK), BLK, 0, stream>>>(fea, Y, t1, u, cls_w, Q, bias2, outp);
}